// Round 5
// baseline (150.767 us; speedup 1.0000x reference)
//
#include <hip/hip_runtime.h>
#include <math.h>

// Problem constants
#define TT 8
#define BB 128
#define GG 256
#define DD 64
#define NCH 4     // D chunks
#define CF4 4     // float4s per cell per chunk (16 floats)
#define ST 4      // UNPADDED stride in float4s; banks handled by XOR-q swizzle (below)

// ws layout: ws[pair*8 + c], c: 0 zdiff, 1 pres, 2 poolc(neg), 3 obj,
//                               4 flow_sq, 5 sum(zp), 6 sum(flow), 7 unused
// Round-2 lesson: contended device atomics in the block epilogue cost ~15 us;
// private ws slots + 1-block final_kernel is strictly better.

__device__ inline float wred(float v) {
#pragma unroll
    for (int off = 32; off > 0; off >>= 1) v += __shfl_xor(v, off, 64);
    return v;
}
__device__ inline float dot4(float4 a, float4 b) {
    return a.x * b.x + a.y * b.y + a.z * b.z + a.w * b.w;
}
__device__ inline float4 fabs4(float4 a) {
    return make_float4(fabsf(a.x), fabsf(a.y), fabsf(a.z), fabsf(a.w));
}
__device__ inline float4 max4(float4 a, float4 b) {
    return make_float4(fmaxf(a.x, b.x), fmaxf(a.y, b.y), fmaxf(a.z, b.z), fmaxf(a.w, b.w));
}
__device__ inline float4 scale4(float4 a, float s) {
    return make_float4(a.x * s, a.y * s, a.z * s, a.w * s);
}
__device__ inline float4 sub4(float4 a, float4 b) {
    return make_float4(a.x - b.x, a.y - b.y, a.z - b.z, a.w - b.w);
}

// XOR-q bank swizzle replacing the ST=5 pad: physical float4 slot for (cell, q) is
// cell*4 + (q ^ ((cell>>1)&3)). For the lane=cell b128 pattern the bank-group index
// is 4*(cell&1) + (q ^ ((cell>>1)&3)): any 8 consecutive cells hit all 8 groups of
// 4 banks exactly once (perfect spread). cell±16 has the same swizzle term, and
// cell±1/±17 neighbor reads also enumerate all 8 groups. 16B alignment preserved
// (unlike fractional padding), so every LDS access stays a true b128.
__device__ inline int swzq(int cell, int q) { return q ^ ((cell >> 1) & 3); }

// 3-wide row max via DPP (verified rounds 1-4). DPP "rows" are 16 lanes, matching
// grid rows (gj = tid & 15). old = v, bound_ctrl = false -> out-of-row lanes get v
// (identity for max): clamped semantics for free.
__device__ inline float rowmax3(float v) {
    int iv = __float_as_int(v);
    int a = __builtin_amdgcn_update_dpp(iv, iv, 0x101, 0xF, 0xF, false); // row_shl:1
    int c = __builtin_amdgcn_update_dpp(iv, iv, 0x111, 0xF, 0xF, false); // row_shr:1
    return fmaxf(v, fmaxf(__int_as_float(a), __int_as_float(c)));
}
__device__ inline float4 rowmax3_4(float4 v) {
    return make_float4(rowmax3(v.x), rowmax3(v.y), rowmax3(v.z), rowmax3(v.w));
}

// VGPR budget notes (rounds 1/3): never pass a min-waves arg (",4" -> 64 VGPR ->
// 326 MB spill); no register prefetch (pfA/pfB -> 136 VGPR, crossed the 128 cliff).
// This structure measures ~120; swizzle + hoisted epilogue loads add ~3-6.
// LDS now ~36 KB -> 4 blocks/CU, matching the 4-waves/SIMD VGPR limit: 1024 block
// slots >= 896-block grid, and 4 independent blocks/CU break barrier lockstep.
__global__ __launch_bounds__(256) void pair_kernel(const float* __restrict__ zw,
                                                   const float* __restrict__ zp,
                                                   const float* __restrict__ flow,
                                                   float* __restrict__ ws) {
    const int pairIdx = blockIdx.x;            // 0 .. 7*BB-1
    const int t = pairIdx >> 7;                // BB = 128
    const int b = pairIdx & (BB - 1);
    const int tid = threadIdx.x;
    const int gi = tid >> 4, gj = tid & 15;
    (void)gj;

    __shared__ float4 shB[GG * ST];            // raw B chunk (neighbor dots), swizzled
    __shared__ float4 shM[GG * ST];            // row-max chunk (col-max pass), swizzled
    __shared__ float pA[GG], pB[GG], nrmB[GG];
    __shared__ float bred[7][4];

    const float4* gA = (const float4*)zw + (size_t)(t * BB + b) * 1024;
    const float4* gB = gA + (size_t)BB * 1024;

    const float pAc = zp[(size_t)(t * BB + b) * GG + tid];
    const float pBc = zp[(size_t)((t + 1) * BB + b) * GG + tid];
    pA[tid] = pAc;                             // visibility covered by chunk-loop syncs
    pB[tid] = pBc;

    // hoisted epilogue loads: issue now, consume after the chunk loop (latency
    // hidden under ~4 chunks of compute; +3 VGPR, below the 128 cliff)
    const float f = flow[(size_t)(t * BB + b) * GG + tid];
    float f7 = 0.f, pC = 0.f;
    if (t == 6) f7 = flow[(size_t)(7 * BB + b) * GG + tid];
    if (t <= 5) pC = zp[(size_t)((t + 2) * BB + b) * GG + tid];

    // 9 wrapped neighbors (jnp.roll semantics) + in-bounds bitmask (clamped ops)
    int nbc[9];
    unsigned inbM = 0;
    {
        int m = 0;
#pragma unroll
        for (int di = -1; di <= 1; di++) {
#pragma unroll
            for (int dj = -1; dj <= 1; dj++) {
                nbc[m] = (((gi + di) & 15) << 4) | ((gj + dj) & 15);
                if (((unsigned)(gi + di) < 16u) && ((unsigned)(gj + dj) < 16u))
                    inbM |= (1u << m);
                m++;
            }
        }
    }

    float zdiff = 0.f, sa = 0.f, sb = 0.f, poolDot = 0.f, poolN = 0.f;
    float dots[9] = {0.f, 0.f, 0.f, 0.f, 0.f, 0.f, 0.f, 0.f, 0.f};
    const int sbase = tid * ST;
    const int sw0 = (tid >> 1) & 3;            // own swizzle term (same for tid +/- 16)

    // IMPORTANT: unroll 1 -- full unroll hoists all chunks' global loads and spills.
#pragma unroll 1
    for (int c = 0; c < NCH; c++) {
        float4 aA[CF4], aB[CF4];
#pragma unroll
        for (int q = 0; q < CF4; q++) {
            aA[q] = gA[tid * 16 + c * 4 + q];
            aB[q] = gB[tid * 16 + c * 4 + q];
        }

        // stage raw B and DPP row-max into separate buffers -> one sync serves both
        float4 rm[CF4];
#pragma unroll
        for (int q = 0; q < CF4; q++) {
            shB[sbase + (q ^ sw0)] = aB[q];
            rm[q] = rowmax3_4(scale4(fabs4(aA[q]), pAc));
            shM[sbase + (q ^ sw0)] = rm[q];
        }
        // register-local stats + center dot (no LDS dependence; keeps waves busy
        // while others reach the barrier)
#pragma unroll
        for (int q = 0; q < CF4; q++) {
            float4 d = sub4(aB[q], aA[q]);
            zdiff += dot4(d, d);
            sa += dot4(aA[q], aA[q]);
            sb += dot4(aB[q], aB[q]);
            dots[4] += dot4(aA[q], aB[q]);
        }
        __syncthreads();

        // neighbor dots: A(center, regs) . B(neighbor, shB) with per-k swizzle
#pragma unroll
        for (int k = 0; k < 9; k++) {
            if (k == 4) continue;
            const int base = nbc[k] * ST;
            const int sk = (nbc[k] >> 1) & 3;
#pragma unroll
            for (int q = 0; q < CF4; q++) dots[k] += dot4(aA[q], shB[base + (q ^ sk)]);
        }
        // clamped col-max of row-max (in place on rm), then pool accumulation
        // ((tid±16)>>1)&3 == sw0, so the column pass reuses the own swizzle term
        if (gi > 0) {
            const int base = (tid - 16) * ST;
#pragma unroll
            for (int q = 0; q < CF4; q++) rm[q] = max4(rm[q], shM[base + (q ^ sw0)]);
        }
        if (gi < 15) {
            const int base = (tid + 16) * ST;
#pragma unroll
            for (int q = 0; q < CF4; q++) rm[q] = max4(rm[q], shM[base + (q ^ sw0)]);
        }
#pragma unroll
        for (int q = 0; q < CF4; q++) {
            poolDot += dot4(rm[q], fabs4(aB[q]));
            poolN += dot4(rm[q], rm[q]);
        }
        __syncthreads();   // all reads of shB/shM done before next chunk's stores
    }

    // ---- epilogues ----
    nrmB[tid] = sqrtf(sb);
    __syncthreads();

    // objects
    float prior_n = fmaxf(sqrtf(sa), 1e-8f);
    float sum_sim = 0.f, max_sim = -1e30f;
    bool has = false;
#pragma unroll
    for (int k = 0; k < 9; k++) {
        float nn = fmaxf(nrmB[nbc[k]], 1e-8f);
        float s = dots[k] / (prior_n * nn);
        if (pB[nbc[k]] > 0.5f) {
            sum_sim += s;
            max_sim = fmaxf(max_sim, s);
            has = true;
        }
    }
    float obj = ((pAc > 0.5f) && has) ? (sum_sim - 5.0f * max_sim) : 0.f;

    // pool
    float na_pool = fmaxf(sqrtf(poolN), 1e-6f);
    float nb_pool = fmaxf(pBc * sqrtf(sb), 1e-6f);
    float poolc = -(pBc * poolDot) / (na_pool * nb_pool) * 0.5f * (pAc + pBc);

    // flow (image t; block t=6 also handles image 7); f/f7 loaded at kernel top
    float mx = pAc;
#pragma unroll
    for (int k = 0; k < 9; k++)
        if (k != 4 && ((inbM >> k) & 1u)) mx = fmaxf(mx, pA[nbc[k]]);
    float fsq = 0.f;
    if (f > 0.5f) { float d = mx - f; fsq = d * d; }
    float szp = pAc, sflow = f;
    if (t == 6) {
        float mxB = pBc;
#pragma unroll
        for (int k = 0; k < 9; k++)
            if (k != 4 && ((inbM >> k) & 1u)) mxB = fmaxf(mxB, pB[nbc[k]]);
        if (f7 > 0.5f) { float d = mxB - f7; fsq += d * d; }
        szp += pBc;
        sflow += f7;
    }

    // pres triple (t, t+1, t+2) for t <= 5; pC loaded at kernel top
    float pres = 0.f;
    if (t <= 5) {
        float s02 = pC - pAc;
        float sim = 1.f - s02 * s02;
        float d2 = pC - pBc, d0 = pAc - pBc;
        pres = sim * (d2 * d2 + d0 * d0);
    }

    // ---- block reduce 7 scalars -> private ws slot (no atomics) ----
    float r[7] = {zdiff, pres, poolc, obj, fsq, szp, sflow};
    int w = tid >> 6, lane = tid & 63;
#pragma unroll
    for (int j = 0; j < 7; j++) {
        float rv = wred(r[j]);
        if (lane == 0) bred[j][w] = rv;
    }
    __syncthreads();
    if (tid < 7)
        ws[pairIdx * 8 + tid] = bred[tid][0] + bred[tid][1] + bred[tid][2] + bred[tid][3];
}

__global__ __launch_bounds__(256) void final_kernel(const float* __restrict__ ws,
                                                    const int* __restrict__ gs,
                                                    float* __restrict__ out) {
    const int tid = threadIdx.x;
    __shared__ float bred[7][4];
    float c[7] = {0.f, 0.f, 0.f, 0.f, 0.f, 0.f, 0.f};
    for (int p = tid; p < (TT - 1) * BB; p += 256) {
        const float* r = ws + p * 8;
#pragma unroll
        for (int j = 0; j < 7; j++) c[j] += r[j];
    }
    int w = tid >> 6, lane = tid & 63;
#pragma unroll
    for (int j = 0; j < 7; j++) {
        float rv = wred(c[j]);
        if (lane == 0) bred[j][w] = rv;
    }
    __syncthreads();
    if (tid == 0) {
        float s[7];
#pragma unroll
        for (int j = 0; j < 7; j++) s[j] = bred[j][0] + bred[j][1] + bred[j][2] + bred[j][3];
        float step = (float)gs[0];
        float scale_obj = fminf(1.f, step / 200000.f);
        float scale_flow = fmaxf(0.f, 1.f - step / 100000.f);
        float flow_loss = s[4] + 100.f * fmaxf(0.f, s[5] - s[6]);
        out[0] = s[0]                       // z_what_loss * ADJ_W
               + s[1]                       // z_pres_loss * PRES_W
               + s[2]                       // pool (already negated) * POOL_W
               + s[3] * scale_obj * 10.0f   // objects * OBJ_W
               + flow_loss * scale_flow;    // FLOW_W = 1
    }
}

extern "C" void kernel_launch(void* const* d_in, const int* in_sizes, int n_in,
                              void* d_out, int out_size, void* d_ws, size_t ws_size,
                              hipStream_t stream) {
    const float* zw = (const float*)d_in[0];
    const float* zp = (const float*)d_in[1];
    const float* fl = (const float*)d_in[2];
    const int* gs = (const int*)d_in[3];
    float* ws = (float*)d_ws;

    pair_kernel<<<(TT - 1) * BB, 256, 0, stream>>>(zw, zp, fl, ws);
    final_kernel<<<1, 256, 0, stream>>>(ws, gs, (float*)d_out);
}